// Round 1
// baseline (16071.686 us; speedup 1.0000x reference)
//
#include <hip/hip_runtime.h>

// GRU T=512 B=256 D=512 H=512 O=256  (input_size == hidden_size)
// Strategy: single persistent scan kernel, 128 wgs (16 batch-groups x 8 col-groups),
// custom grid barrier (2/step). x@W folded into the scan (no big ws needed).
// All cross-wg state (h, r*h) via system-scope relaxed atomics (LLC-coherent,
// no acquire fences -> weights stay resident in per-XCD L2 across all steps).

#define T_ 512
#define B_ 256
#define D_ 512
#define H_ 512
#define O_ 256

#define NWG 128
#define ROWS 16   // batch rows per wg
#define GC 64     // cols per gate per wg

typedef __attribute__((ext_vector_type(8))) short short8;
typedef __attribute__((ext_vector_type(4))) float f32x4;

__device__ __forceinline__ unsigned short f2bf(float f) {
  unsigned u = __float_as_uint(f);
  u = (u + 0x7FFFu + ((u >> 16) & 1u)) >> 16;   // RNE
  return (unsigned short)u;
}
__device__ __forceinline__ float bf2f(unsigned short h) {
  return __uint_as_float(((unsigned)h) << 16);
}

__device__ __forceinline__ void gridbar(int* bar, int target) {
  __syncthreads();  // drains vmcnt: all wg stores (sc0sc1 -> LLC) complete
  if (threadIdx.x == 0) {
    __hip_atomic_fetch_add(bar, 1, __ATOMIC_RELEASE, __HIP_MEMORY_SCOPE_SYSTEM);
    while (__hip_atomic_load(bar, __ATOMIC_RELAXED, __HIP_MEMORY_SCOPE_SYSTEM) < target) {
      __builtin_amdgcn_s_sleep(2);
    }
  }
  __syncthreads();
}

// ---- prep: transpose weights to N-major bf16, combine biases, zero h, zero barrier
__global__ void prep_kernel(const float* wz, const float* uz,
                            const float* wr, const float* ur,
                            const float* wh, const float* uh,
                            const float* bz, const float* ubz,
                            const float* br, const float* ubr,
                            const float* bh, const float* ubh,
                            unsigned short* WT, unsigned short* UT,
                            float* cb, unsigned short* hbuf, int* bar)
{
  int idx = blockIdx.x * 256 + threadIdx.x;
  if (idx < 1536 * 512) {
    int n = idx >> 9;          // output col 0..1535 (z|r|h)
    int k = idx & 511;
    int g = n >> 9;            // gate
    int c = n & 511;
    const float* w = (g == 0) ? wz : (g == 1) ? wr : wh;
    const float* u = (g == 0) ? uz : (g == 1) ? ur : uh;
    WT[idx] = f2bf(w[k * H_ + c]);   // WT[n][k] = W[k][n]
    UT[idx] = f2bf(u[k * H_ + c]);
  }
  if (idx < 1536) {
    int g = idx >> 9, c = idx & 511;
    const float* b  = (g == 0) ? bz  : (g == 1) ? br  : bh;
    const float* ub = (g == 0) ? ubz : (g == 1) ? ubr : ubh;
    cb[idx] = b[c] + ub[c];
  }
  if (idx < B_ * H_) hbuf[idx] = 0;
  if (idx == 0) *bar = 0;
}

// ---- persistent scan kernel
__global__ __launch_bounds__(256, 2) void gru_scan(
    const float* __restrict__ x,            // [T][B][D] fp32
    const unsigned short* __restrict__ WT,  // [1536][512] bf16 N-major
    const unsigned short* __restrict__ UT,  // [1536][512] bf16 N-major
    const float* __restrict__ cb,           // [1536] combined bias
    unsigned short* hbuf,                   // [B][H] bf16 (system-coherent access)
    unsigned short* rhbuf,                  // [B][H] bf16 (system-coherent access)
    int* bar)
{
  __shared__ __align__(16) unsigned short a_lds[2][ROWS][520]; // [0]=x_t, [1]=h / rh (pad 520: bank-conflict-free)
  __shared__ float z_lds[ROWS][GC];
  __shared__ float gh_lds[ROWS][GC];
  __shared__ float xh_lds[ROWS][GC];

  const int wgid = blockIdx.x;
  const int bg = wgid >> 3;       // 0..15
  const int cg = wgid & 7;        // 0..7
  const int r0 = bg * ROWS;
  const int c0 = cg * GC;
  const int tid = threadIdx.x;
  const int wid = tid >> 6;       // wave 0..3
  const int lane = tid & 63;
  const int l16 = lane & 15;
  const int lhi = lane >> 4;      // 0..3

  // per-wave tile column base: wave handles one 16-col tile of each gate (balanced: 5 MFMA/k-step)
  const int ct = c0 + wid * 16;
  const unsigned short* WTz = WT + (size_t)(ct)        * 512;
  const unsigned short* UTz = UT + (size_t)(ct)        * 512;
  const unsigned short* WTr = WT + (size_t)(512 + ct)  * 512;
  const unsigned short* UTr = UT + (size_t)(512 + ct)  * 512;
  const unsigned short* WTh = WT + (size_t)(1024 + ct) * 512;
  const unsigned short* UTh = UT + (size_t)(1024 + ct) * 512;

  const int gcz  = ct + l16;      // this lane's gate column (0..511)
  const int lcol = ct - c0 + l16; // 0..63 within wg
  const float cbz = cb[gcz];
  const float cbr = cb[512 + gcz];
  const float cbh = cb[1024 + gcz];

  int bar_target = 0;

  for (int t = 0; t < T_; ++t) {
    // ---- stage x_t (fp32->bf16) and h into LDS ----
    {
      const float4* xs = (const float4*)(x + ((size_t)t * B_ + r0) * D_);
      #pragma unroll
      for (int i = 0; i < 8; ++i) {              // 16 rows * 128 float4
        int g = tid + i * 256;
        int row = g >> 7;
        int c4 = g & 127;
        float4 v = xs[row * 128 + c4];
        unsigned short* dst = &a_lds[0][row][c4 * 4];
        dst[0] = f2bf(v.x); dst[1] = f2bf(v.y); dst[2] = f2bf(v.z); dst[3] = f2bf(v.w);
      }
      const unsigned int* hs = (const unsigned int*)(hbuf + (size_t)r0 * H_);
      #pragma unroll
      for (int i = 0; i < 16; ++i) {             // 16 rows * 256 dwords
        int g = tid + i * 256;
        int row = g >> 8;
        int cd = g & 255;
        unsigned int v = __hip_atomic_load(hs + row * 256 + cd,
                                           __ATOMIC_RELAXED, __HIP_MEMORY_SCOPE_SYSTEM);
        *(unsigned int*)&a_lds[1][row][cd * 2] = v;
      }
    }
    __syncthreads();

    // ---- phase A: S = x@W + h@U for z,r and xh = x@W_h ----
    f32x4 accz = {0.f, 0.f, 0.f, 0.f};
    f32x4 accr = {0.f, 0.f, 0.f, 0.f};
    f32x4 acch = {0.f, 0.f, 0.f, 0.f};
    {
      const unsigned short* xrow = &a_lds[0][l16][0];
      const unsigned short* hrow = &a_lds[1][l16][0];
      #pragma unroll 4
      for (int k0 = 0; k0 < 512; k0 += 32) {
        int ko = k0 + lhi * 8;
        short8 ax = *(const short8*)(xrow + ko);
        short8 ah = *(const short8*)(hrow + ko);
        short8 bwz = *(const short8*)(WTz + l16 * 512 + ko);
        short8 buz = *(const short8*)(UTz + l16 * 512 + ko);
        short8 bwr = *(const short8*)(WTr + l16 * 512 + ko);
        short8 bur = *(const short8*)(UTr + l16 * 512 + ko);
        short8 bwh = *(const short8*)(WTh + l16 * 512 + ko);
        accz = __builtin_amdgcn_mfma_f32_16x16x32_bf16(ax, bwz, accz, 0, 0, 0);
        accz = __builtin_amdgcn_mfma_f32_16x16x32_bf16(ah, buz, accz, 0, 0, 0);
        accr = __builtin_amdgcn_mfma_f32_16x16x32_bf16(ax, bwr, accr, 0, 0, 0);
        accr = __builtin_amdgcn_mfma_f32_16x16x32_bf16(ah, bur, accr, 0, 0, 0);
        acch = __builtin_amdgcn_mfma_f32_16x16x32_bf16(ax, bwh, acch, 0, 0, 0);
      }
    }
    // epilogue A: gates; keep z,(1-z)h,xh in LDS; publish r*h (bf16) system-coherent
    {
      #pragma unroll
      for (int i = 0; i < 4; ++i) {
        int lrow = lhi * 4 + i;                  // C/D: row=(lane>>4)*4+i, col=lane&15
        float h_old = bf2f(a_lds[1][lrow][gcz]);
        float zv = 1.f / (1.f + __expf(-(accz[i] + cbz)));
        float rv = 1.f / (1.f + __expf(-(accr[i] + cbr)));
        z_lds[lrow][lcol]  = zv;
        gh_lds[lrow][lcol] = (1.f - zv) * h_old;
        xh_lds[lrow][lcol] = acch[i] + cbh;
        __hip_atomic_store(rhbuf + (size_t)(r0 + lrow) * H_ + gcz, f2bf(rv * h_old),
                           __ATOMIC_RELAXED, __HIP_MEMORY_SCOPE_SYSTEM);
      }
    }
    bar_target += NWG;
    gridbar(bar, bar_target);

    // ---- phase B: hhat = tanh(rh@U_h + xh); h = (1-z)h + z*hhat ----
    {
      const unsigned int* rs = (const unsigned int*)(rhbuf + (size_t)r0 * H_);
      #pragma unroll
      for (int i = 0; i < 16; ++i) {
        int g = tid + i * 256;
        int row = g >> 8;
        int cd = g & 255;
        unsigned int v = __hip_atomic_load(rs + row * 256 + cd,
                                           __ATOMIC_RELAXED, __HIP_MEMORY_SCOPE_SYSTEM);
        *(unsigned int*)&a_lds[1][row][cd * 2] = v;
      }
    }
    __syncthreads();
    f32x4 acc2 = {0.f, 0.f, 0.f, 0.f};
    {
      const unsigned short* rrow = &a_lds[1][l16][0];
      #pragma unroll 4
      for (int k0 = 0; k0 < 512; k0 += 32) {
        int ko = k0 + lhi * 8;
        short8 ar = *(const short8*)(rrow + ko);
        short8 bu = *(const short8*)(UTh + l16 * 512 + ko);
        acc2 = __builtin_amdgcn_mfma_f32_16x16x32_bf16(ar, bu, acc2, 0, 0, 0);
      }
    }
    {
      #pragma unroll
      for (int i = 0; i < 4; ++i) {
        int lrow = lhi * 4 + i;
        float s = acc2[i] + xh_lds[lrow][lcol];
        float hh = tanhf(s);
        float hn = gh_lds[lrow][lcol] + z_lds[lrow][lcol] * hh;
        __hip_atomic_store(hbuf + (size_t)(r0 + lrow) * H_ + (ct + l16), f2bf(hn),
                           __ATOMIC_RELAXED, __HIP_MEMORY_SCOPE_SYSTEM);
      }
    }
    bar_target += NWG;
    gridbar(bar, bar_target);
  }
}

// ---- final FC: out[b][o] = sum_k h_T[b][k] * fc_w[k][o] + fc_b[o]
__global__ void fc_kernel(const unsigned short* __restrict__ hbuf,
                          const float* __restrict__ fcw,
                          const float* __restrict__ fcb,
                          float* __restrict__ out)
{
  int b = blockIdx.x;
  int o = threadIdx.x;
  float s = fcb[o];
  const unsigned short* hr = hbuf + (size_t)b * H_;
  #pragma unroll 8
  for (int k = 0; k < H_; ++k)
    s = fmaf(bf2f(hr[k]), fcw[k * O_ + o], s);
  out[b * O_ + o] = s;
}

extern "C" void kernel_launch(void* const* d_in, const int* in_sizes, int n_in,
                              void* d_out, int out_size, void* d_ws, size_t ws_size,
                              hipStream_t stream)
{
  const float* x    = (const float*)d_in[0];
  const float* w_z  = (const float*)d_in[1];
  const float* b_z  = (const float*)d_in[2];
  const float* u_z  = (const float*)d_in[3];
  const float* ub_z = (const float*)d_in[4];
  const float* w_r  = (const float*)d_in[5];
  const float* b_r  = (const float*)d_in[6];
  const float* u_r  = (const float*)d_in[7];
  const float* ub_r = (const float*)d_in[8];
  const float* w_h  = (const float*)d_in[9];
  const float* b_h  = (const float*)d_in[10];
  const float* u_h  = (const float*)d_in[11];
  const float* ub_h = (const float*)d_in[12];
  const float* fc_w = (const float*)d_in[13];
  const float* fc_b = (const float*)d_in[14];
  float* out = (float*)d_out;

  char* ws = (char*)d_ws;
  unsigned short* WT = (unsigned short*)ws;  ws += (size_t)1536 * 512 * 2;
  unsigned short* UT = (unsigned short*)ws;  ws += (size_t)1536 * 512 * 2;
  float* cb = (float*)ws;                    ws += 1536 * 4;
  unsigned short* hbuf = (unsigned short*)ws;  ws += (size_t)B_ * H_ * 2;
  unsigned short* rhbuf = (unsigned short*)ws; ws += (size_t)B_ * H_ * 2;
  ws = (char*)(((size_t)ws + 255) & ~(size_t)255);
  int* bar = (int*)ws;

  prep_kernel<<<3072, 256, 0, stream>>>(w_z, u_z, w_r, u_r, w_h, u_h,
                                        b_z, ub_z, b_r, ub_r, b_h, ub_h,
                                        WT, UT, cb, hbuf, bar);
  gru_scan<<<NWG, 256, 0, stream>>>(x, WT, UT, cb, hbuf, rhbuf, bar);
  fc_kernel<<<B_, O_, 0, stream>>>(hbuf, fc_w, fc_b, out);
}

// Round 2
// 9293.189 us; speedup vs baseline: 1.7294x; 1.7294x over previous
//
#include <hip/hip_runtime.h>

// GRU T=512 B=256 D=512 H=512 O=256
// Persistent scan kernel, 128 wgs = 16 batch-groups x 8 col-groups.
// R2: group-local barriers (8 wgs each, one per batch-group), all atomics
// relaxed+agent scope (no buffer_wbl2 / buffer_inv cache maintenance),
// x_{t+1} register prefetch, 8B coherent staging loads.

#define T_ 512
#define B_ 256
#define D_ 512
#define H_ 512
#define O_ 256

#define NWG 128
#define ROWS 16   // batch rows per wg
#define GC 64     // cols per gate per wg
#define GRP 8     // wgs per barrier group (one batch-group)

typedef __attribute__((ext_vector_type(8))) short short8;
typedef __attribute__((ext_vector_type(4))) float f32x4;

__device__ __forceinline__ unsigned short f2bf(float f) {
  unsigned u = __float_as_uint(f);
  u = (u + 0x7FFFu + ((u >> 16) & 1u)) >> 16;   // RNE
  return (unsigned short)u;
}
__device__ __forceinline__ float bf2f(unsigned short h) {
  return __uint_as_float(((unsigned)h) << 16);
}

// group barrier: relaxed agent atomics only. __syncthreads() before the add
// drains vmcnt for ALL waves of this wg (compiler emits s_waitcnt vmcnt(0)
// before s_barrier), so every sc-flagged data store is at the LLC before the
// counter increments. Consumers read data with sc-flagged loads -> coherent.
__device__ __forceinline__ void groupbar(int* ctr, int target) {
  __syncthreads();
  if (threadIdx.x == 0) {
    __hip_atomic_fetch_add(ctr, 1, __ATOMIC_RELAXED, __HIP_MEMORY_SCOPE_AGENT);
    while (__hip_atomic_load(ctr, __ATOMIC_RELAXED, __HIP_MEMORY_SCOPE_AGENT) < target) {
      __builtin_amdgcn_s_sleep(2);
    }
  }
  __syncthreads();
}

// ---- prep: transpose weights to N-major bf16, combine biases, zero h + barriers
__global__ void prep_kernel(const float* wz, const float* uz,
                            const float* wr, const float* ur,
                            const float* wh, const float* uh,
                            const float* bz, const float* ubz,
                            const float* br, const float* ubr,
                            const float* bh, const float* ubh,
                            unsigned short* WT, unsigned short* UT,
                            float* cb, unsigned short* hbuf, int* bar)
{
  int idx = blockIdx.x * 256 + threadIdx.x;
  if (idx < 1536 * 512) {
    int n = idx >> 9;          // output col 0..1535 (z|r|h)
    int k = idx & 511;
    int g = n >> 9;            // gate
    int c = n & 511;
    const float* w = (g == 0) ? wz : (g == 1) ? wr : wh;
    const float* u = (g == 0) ? uz : (g == 1) ? ur : uh;
    WT[idx] = f2bf(w[k * H_ + c]);   // WT[n][k] = W[k][n]
    UT[idx] = f2bf(u[k * H_ + c]);
  }
  if (idx < 1536) {
    int g = idx >> 9, c = idx & 511;
    const float* b  = (g == 0) ? bz  : (g == 1) ? br  : bh;
    const float* ub = (g == 0) ? ubz : (g == 1) ? ubr : ubh;
    cb[idx] = b[c] + ub[c];
  }
  if (idx < B_ * H_) hbuf[idx] = 0;
  if (idx < 16 * 64) bar[idx] = 0;   // 16 group counters, 256B apart
}

// ---- persistent scan kernel
__global__ __launch_bounds__(256, 1) void gru_scan(
    const float* __restrict__ x,            // [T][B][D] fp32
    const unsigned short* __restrict__ WT,  // [1536][512] bf16 N-major
    const unsigned short* __restrict__ UT,  // [1536][512] bf16 N-major
    const float* __restrict__ cb,           // [1536] combined bias
    unsigned short* hbuf,                   // [B][H] bf16 (LLC-coherent access)
    unsigned short* rhbuf,                  // [B][H] bf16 (LLC-coherent access)
    int* bar)
{
  __shared__ __align__(16) unsigned short a_lds[2][ROWS][520]; // [0]=x_t, [1]=h / rh
  __shared__ float z_lds[ROWS][GC];
  __shared__ float gh_lds[ROWS][GC];
  __shared__ float xh_lds[ROWS][GC];

  const int wgid = blockIdx.x;
  const int bg = wgid >> 3;       // 0..15
  const int cg = wgid & 7;        // 0..7
  const int r0 = bg * ROWS;
  const int c0 = cg * GC;
  const int tid = threadIdx.x;
  const int wid = tid >> 6;       // wave 0..3
  const int lane = tid & 63;
  const int l16 = lane & 15;
  const int lhi = lane >> 4;      // 0..3

  int* gbar = bar + bg * 64;      // this batch-group's counter (own cacheline)

  const int ct = c0 + wid * 16;   // this wave's 16-col tile base (per gate)
  const unsigned short* WTz = WT + (size_t)(ct)        * 512;
  const unsigned short* UTz = UT + (size_t)(ct)        * 512;
  const unsigned short* WTr = WT + (size_t)(512 + ct)  * 512;
  const unsigned short* UTr = UT + (size_t)(512 + ct)  * 512;
  const unsigned short* WTh = WT + (size_t)(1024 + ct) * 512;
  const unsigned short* UTh = UT + (size_t)(1024 + ct) * 512;

  const int gcz  = ct + l16;      // this lane's gate column (0..511)
  const int lcol = ct - c0 + l16; // 0..63 within wg
  const float cbz = cb[gcz];
  const float cbr = cb[512 + gcz];
  const float cbh = cb[1024 + gcz];

  int bar_target = 0;

  // prologue: prefetch x_0 into registers
  float4 xr[8];
  {
    const float4* xs = (const float4*)(x + (size_t)r0 * D_);
    #pragma unroll
    for (int i = 0; i < 8; ++i) {
      int g = tid + i * 256;
      xr[i] = xs[(g >> 7) * 128 + (g & 127)];
    }
  }

  for (int t = 0; t < T_; ++t) {
    // ---- stage x_t (regs -> bf16 LDS) and h (LLC -> LDS) ----
    {
      #pragma unroll
      for (int i = 0; i < 8; ++i) {
        int g = tid + i * 256;
        int row = g >> 7;
        int c4 = g & 127;
        float4 v = xr[i];
        unsigned short tmp[4] = { f2bf(v.x), f2bf(v.y), f2bf(v.z), f2bf(v.w) };
        *(unsigned long long*)&a_lds[0][row][c4 * 4] = *(unsigned long long*)tmp;
      }
      const unsigned long long* hs = (const unsigned long long*)(hbuf + (size_t)r0 * H_);
      #pragma unroll
      for (int i = 0; i < 8; ++i) {          // 16 rows * 128 qwords
        int g = tid + i * 256;
        int row = g >> 7;
        int q = g & 127;
        unsigned long long v = __hip_atomic_load(hs + row * 128 + q,
                                                 __ATOMIC_RELAXED, __HIP_MEMORY_SCOPE_AGENT);
        *(unsigned long long*)&a_lds[1][row][q * 4] = v;
      }
    }
    __syncthreads();

    // prefetch x_{t+1} into regs (completes under phase A MFMA / barrier)
    {
      int tn = (t + 1 < T_) ? (t + 1) : t;
      const float4* xs = (const float4*)(x + ((size_t)tn * B_ + r0) * D_);
      #pragma unroll
      for (int i = 0; i < 8; ++i) {
        int g = tid + i * 256;
        xr[i] = xs[(g >> 7) * 128 + (g & 127)];
      }
    }

    // ---- phase A: accz=x@Wz+h@Uz, accr=x@Wr+h@Ur, acch=x@Wh ----
    f32x4 accz = {0.f, 0.f, 0.f, 0.f};
    f32x4 accr = {0.f, 0.f, 0.f, 0.f};
    f32x4 acch = {0.f, 0.f, 0.f, 0.f};
    {
      const unsigned short* xrow = &a_lds[0][l16][0];
      const unsigned short* hrow = &a_lds[1][l16][0];
      #pragma unroll 8
      for (int k0 = 0; k0 < 512; k0 += 32) {
        int ko = k0 + lhi * 8;
        short8 ax = *(const short8*)(xrow + ko);
        short8 ah = *(const short8*)(hrow + ko);
        short8 bwz = *(const short8*)(WTz + l16 * 512 + ko);
        short8 buz = *(const short8*)(UTz + l16 * 512 + ko);
        short8 bwr = *(const short8*)(WTr + l16 * 512 + ko);
        short8 bur = *(const short8*)(UTr + l16 * 512 + ko);
        short8 bwh = *(const short8*)(WTh + l16 * 512 + ko);
        accz = __builtin_amdgcn_mfma_f32_16x16x32_bf16(ax, bwz, accz, 0, 0, 0);
        accz = __builtin_amdgcn_mfma_f32_16x16x32_bf16(ah, buz, accz, 0, 0, 0);
        accr = __builtin_amdgcn_mfma_f32_16x16x32_bf16(ax, bwr, accr, 0, 0, 0);
        accr = __builtin_amdgcn_mfma_f32_16x16x32_bf16(ah, bur, accr, 0, 0, 0);
        acch = __builtin_amdgcn_mfma_f32_16x16x32_bf16(ax, bwh, acch, 0, 0, 0);
      }
    }
    // epilogue A: gates; keep z,(1-z)h,xh in LDS; publish r*h (bf16, LLC)
    {
      #pragma unroll
      for (int i = 0; i < 4; ++i) {
        int lrow = lhi * 4 + i;                  // C/D: row=(lane>>4)*4+i, col=lane&15
        float h_old = bf2f(a_lds[1][lrow][gcz]);
        float zv = 1.f / (1.f + __expf(-(accz[i] + cbz)));
        float rv = 1.f / (1.f + __expf(-(accr[i] + cbr)));
        z_lds[lrow][lcol]  = zv;
        gh_lds[lrow][lcol] = (1.f - zv) * h_old;
        xh_lds[lrow][lcol] = acch[i] + cbh;
        __hip_atomic_store(rhbuf + (size_t)(r0 + lrow) * H_ + gcz, f2bf(rv * h_old),
                           __ATOMIC_RELAXED, __HIP_MEMORY_SCOPE_AGENT);
      }
    }
    bar_target += GRP;
    groupbar(gbar, bar_target);

    // ---- phase B: hhat = tanh(rh@U_h + xh); h = (1-z)h + z*hhat ----
    {
      const unsigned long long* rs = (const unsigned long long*)(rhbuf + (size_t)r0 * H_);
      #pragma unroll
      for (int i = 0; i < 8; ++i) {
        int g = tid + i * 256;
        int row = g >> 7;
        int q = g & 127;
        unsigned long long v = __hip_atomic_load(rs + row * 128 + q,
                                                 __ATOMIC_RELAXED, __HIP_MEMORY_SCOPE_AGENT);
        *(unsigned long long*)&a_lds[1][row][q * 4] = v;
      }
    }
    __syncthreads();
    f32x4 acc2 = {0.f, 0.f, 0.f, 0.f};
    {
      const unsigned short* rrow = &a_lds[1][l16][0];
      #pragma unroll 8
      for (int k0 = 0; k0 < 512; k0 += 32) {
        int ko = k0 + lhi * 8;
        short8 ar = *(const short8*)(rrow + ko);
        short8 bu = *(const short8*)(UTh + l16 * 512 + ko);
        acc2 = __builtin_amdgcn_mfma_f32_16x16x32_bf16(ar, bu, acc2, 0, 0, 0);
      }
    }
    {
      #pragma unroll
      for (int i = 0; i < 4; ++i) {
        int lrow = lhi * 4 + i;
        float s = acc2[i] + xh_lds[lrow][lcol];
        float hh = tanhf(s);
        float hn = gh_lds[lrow][lcol] + z_lds[lrow][lcol] * hh;
        __hip_atomic_store(hbuf + (size_t)(r0 + lrow) * H_ + (ct + l16), f2bf(hn),
                           __ATOMIC_RELAXED, __HIP_MEMORY_SCOPE_AGENT);
      }
    }
    bar_target += GRP;
    groupbar(gbar, bar_target);
  }
}

// ---- final FC: out[b][o] = sum_k h_T[b][k] * fc_w[k][o] + fc_b[o]
__global__ void fc_kernel(const unsigned short* __restrict__ hbuf,
                          const float* __restrict__ fcw,
                          const float* __restrict__ fcb,
                          float* __restrict__ out)
{
  int b = blockIdx.x;
  int o = threadIdx.x;
  float s = fcb[o];
  const unsigned short* hr = hbuf + (size_t)b * H_;
  #pragma unroll 8
  for (int k = 0; k < H_; ++k)
    s = fmaf(bf2f(hr[k]), fcw[k * O_ + o], s);
  out[b * O_ + o] = s;
}

extern "C" void kernel_launch(void* const* d_in, const int* in_sizes, int n_in,
                              void* d_out, int out_size, void* d_ws, size_t ws_size,
                              hipStream_t stream)
{
  const float* x    = (const float*)d_in[0];
  const float* w_z  = (const float*)d_in[1];
  const float* b_z  = (const float*)d_in[2];
  const float* u_z  = (const float*)d_in[3];
  const float* ub_z = (const float*)d_in[4];
  const float* w_r  = (const float*)d_in[5];
  const float* b_r  = (const float*)d_in[6];
  const float* u_r  = (const float*)d_in[7];
  const float* ub_r = (const float*)d_in[8];
  const float* w_h  = (const float*)d_in[9];
  const float* b_h  = (const float*)d_in[10];
  const float* u_h  = (const float*)d_in[11];
  const float* ub_h = (const float*)d_in[12];
  const float* fc_w = (const float*)d_in[13];
  const float* fc_b = (const float*)d_in[14];
  float* out = (float*)d_out;

  char* ws = (char*)d_ws;
  unsigned short* WT = (unsigned short*)ws;  ws += (size_t)1536 * 512 * 2;
  unsigned short* UT = (unsigned short*)ws;  ws += (size_t)1536 * 512 * 2;
  float* cb = (float*)ws;                    ws += 1536 * 4;
  unsigned short* hbuf = (unsigned short*)ws;  ws += (size_t)B_ * H_ * 2;
  unsigned short* rhbuf = (unsigned short*)ws; ws += (size_t)B_ * H_ * 2;
  ws = (char*)(((size_t)ws + 255) & ~(size_t)255);
  int* bar = (int*)ws;

  prep_kernel<<<3072, 256, 0, stream>>>(w_z, u_z, w_r, u_r, w_h, u_h,
                                        b_z, ub_z, b_r, ub_r, b_h, ub_h,
                                        WT, UT, cb, hbuf, bar);
  gru_scan<<<NWG, 256, 0, stream>>>(x, WT, UT, cb, hbuf, rhbuf, bar);
  fc_kernel<<<B_, O_, 0, stream>>>(hbuf, fc_w, fc_b, out);
}

// Round 3
// 3035.518 us; speedup vs baseline: 5.2945x; 3.0615x over previous
//
#include <hip/hip_runtime.h>

// GRU T=512 B=256 D=512 H=512 O=256
// R3: register-resident U weights, x@W computed in barrier bubbles (1 step ahead),
// RMW-free per-wg slot barrier (8 parallel read-only polls), latency slots:
// every MALL round trip overlapped with a 16-MFMA x@W chunk.

#define T_ 512
#define B_ 256
#define D_ 512
#define H_ 512
#define O_ 256

#define NWG 128
#define ROWS 16   // batch rows per wg
#define GC 64     // cols per gate per wg
#define GRP 8     // wgs per barrier group (one batch-group)

typedef __attribute__((ext_vector_type(8))) short short8;
typedef __attribute__((ext_vector_type(4))) float f32x4;

__device__ __forceinline__ unsigned short f2bf(float f) {
  unsigned u = __float_as_uint(f);
  u = (u + 0x7FFFu + ((u >> 16) & 1u)) >> 16;   // RNE
  return (unsigned short)u;
}
__device__ __forceinline__ float bf2f(unsigned short h) {
  return __uint_as_float(((unsigned)h) << 16);
}

// ---- prep: transpose weights to N-major bf16, combine biases, zero h + slots
__global__ void prep_kernel(const float* wz, const float* uz,
                            const float* wr, const float* ur,
                            const float* wh, const float* uh,
                            const float* bz, const float* ubz,
                            const float* br, const float* ubr,
                            const float* bh, const float* ubh,
                            unsigned short* WT, unsigned short* UT,
                            float* cb, unsigned short* hbuf, int* bar)
{
  int idx = blockIdx.x * 256 + threadIdx.x;
  if (idx < 1536 * 512) {
    int n = idx >> 9;          // output col 0..1535 (z|r|h)
    int k = idx & 511;
    int g = n >> 9;            // gate
    int c = n & 511;
    const float* w = (g == 0) ? wz : (g == 1) ? wr : wh;
    const float* u = (g == 0) ? uz : (g == 1) ? ur : uh;
    WT[idx] = f2bf(w[k * H_ + c]);   // WT[n][k] = W[k][n]
    UT[idx] = f2bf(u[k * H_ + c]);
  }
  if (idx < 1536) {
    int g = idx >> 9, c = idx & 511;
    const float* b  = (g == 0) ? bz  : (g == 1) ? br  : bh;
    const float* ub = (g == 0) ? ubz : (g == 1) ? ubr : ubh;
    cb[idx] = b[c] + ub[c];
  }
  if (idx < B_ * H_) hbuf[idx] = 0;
  if (idx < 16 * GRP * 32) bar[idx] = 0;   // 16 groups x 8 slots x 128B
}

// ---- persistent scan kernel
__global__ __launch_bounds__(256, 1) void gru_scan(
    const float* __restrict__ x,            // [T][B][D] fp32
    const unsigned short* __restrict__ WT,  // [1536][512] bf16 N-major
    const unsigned short* __restrict__ UT,  // [1536][512] bf16 N-major
    const float* __restrict__ cb,           // [1536] combined bias
    unsigned short* hbuf,                   // [B][H] bf16 (LLC-coherent access)
    unsigned short* rhbuf,                  // [B][H] bf16 (LLC-coherent access)
    int* bar)
{
  __shared__ __align__(16) unsigned short x_lds[2][ROWS][520];
  __shared__ __align__(16) unsigned short h_lds[ROWS][520];

  const int wgid = blockIdx.x;
  const int bg = wgid >> 3;       // 0..15
  const int cg = wgid & 7;        // 0..7
  const int r0 = bg * ROWS;
  const int c0 = cg * GC;
  const int tid = threadIdx.x;
  const int wid = tid >> 6;       // wave 0..3
  const int lane = tid & 63;
  const int l16 = lane & 15;
  const int lhi = lane >> 4;      // 0..3

  int* slots  = bar + bg * (GRP * 32);
  int* myslot = slots + cg * 32;

  const int ct = c0 + wid * 16;   // this wave's 16-col tile base (per gate)
  const unsigned short* WTz = WT + (size_t)(ct)        * 512;
  const unsigned short* WTr = WT + (size_t)(512 + ct)  * 512;
  const unsigned short* WTh = WT + (size_t)(1024 + ct) * 512;
  const unsigned short* UTz = UT + (size_t)(ct)        * 512;
  const unsigned short* UTr = UT + (size_t)(512 + ct)  * 512;
  const unsigned short* UTh = UT + (size_t)(1024 + ct) * 512;

  const int gcz  = ct + l16;      // this lane's gate column (0..511)
  const float cbz = cb[gcz];
  const float cbr = cb[512 + gcz];
  const float cbh = cb[1024 + gcz];

  // ---- U weights -> registers (B-fragments, 192 VGPRs) ----
  short8 uzr[16], urr[16], uhr[16];
  #pragma unroll
  for (int k = 0; k < 16; ++k) {
    const int off = l16 * 512 + k * 32 + lhi * 8;
    uzr[k] = *(const short8*)(UTz + off);
    urr[k] = *(const short8*)(UTr + off);
    uhr[k] = *(const short8*)(UTh + off);
  }

  // ---- prologue: x_0 -> LDS, x_1 -> regs, h_lds = 0, x_0@W -> accumulators ----
  float4 xr4[8];
  {
    const float4* xs = (const float4*)(x + (size_t)r0 * D_);
    #pragma unroll
    for (int i = 0; i < 8; ++i) {
      int g = tid + i * 256;
      float4 v = xs[(g >> 7) * 128 + (g & 127)];
      unsigned short tmp[4] = { f2bf(v.x), f2bf(v.y), f2bf(v.z), f2bf(v.w) };
      *(unsigned long long*)&x_lds[0][g >> 7][(g & 127) * 4] = *(unsigned long long*)tmp;
      *(unsigned long long*)&h_lds[g >> 7][(g & 127) * 4] = 0ull;
    }
    const float4* xs1 = (const float4*)(x + ((size_t)B_ + r0) * D_);
    #pragma unroll
    for (int i = 0; i < 8; ++i) {
      int g = tid + i * 256;
      xr4[i] = xs1[(g >> 7) * 128 + (g & 127)];
    }
  }
  __syncthreads();

  f32x4 xzc = {0.f,0.f,0.f,0.f}, xrc = {0.f,0.f,0.f,0.f}, xhc = {0.f,0.f,0.f,0.f};
  {
    const unsigned short* xrow = &x_lds[0][l16][0];
    #pragma unroll
    for (int k = 0; k < 16; ++k) {
      int ko = k * 32 + lhi * 8;
      short8 ax = *(const short8*)(xrow + ko);
      int boff = l16 * 512 + ko;
      short8 wz = *(const short8*)(WTz + boff);
      short8 wr = *(const short8*)(WTr + boff);
      short8 wh = *(const short8*)(WTh + boff);
      xzc = __builtin_amdgcn_mfma_f32_16x16x32_bf16(ax, wz, xzc, 0, 0, 0);
      xrc = __builtin_amdgcn_mfma_f32_16x16x32_bf16(ax, wr, xrc, 0, 0, 0);
      xhc = __builtin_amdgcn_mfma_f32_16x16x32_bf16(ax, wh, xhc, 0, 0, 0);
    }
  }

  for (int t = 0; t < T_; ++t) {
    const int p = t & 1;
    // ---- phase A: h@Uz, h@Ur (U in regs, A from h_lds) ----
    f32x4 accz = {0.f,0.f,0.f,0.f};
    f32x4 accr = {0.f,0.f,0.f,0.f};
    {
      const unsigned short* hrow = &h_lds[l16][0];
      #pragma unroll
      for (int k = 0; k < 16; ++k) {
        short8 ah = *(const short8*)(hrow + k * 32 + lhi * 8);
        accz = __builtin_amdgcn_mfma_f32_16x16x32_bf16(ah, uzr[k], accz, 0, 0, 0);
        accr = __builtin_amdgcn_mfma_f32_16x16x32_bf16(ah, urr[k], accr, 0, 0, 0);
      }
    }
    // epilogue A: z, r in regs; publish r*h
    f32x4 z4, gh4;
    {
      #pragma unroll
      for (int i = 0; i < 4; ++i) {
        int lrow = lhi * 4 + i;                  // C/D: row=(lane>>4)*4+i, col=lane&15
        float h_old = bf2f(h_lds[lrow][gcz]);
        float zv = 1.f / (1.f + __expf(-(accz[i] + xzc[i] + cbz)));
        float rv = 1.f / (1.f + __expf(-(accr[i] + xrc[i] + cbr)));
        z4[i]  = zv;
        gh4[i] = (1.f - zv) * h_old;
        __hip_atomic_store(rhbuf + (size_t)(r0 + lrow) * H_ + gcz, f2bf(rv * h_old),
                           __ATOMIC_RELAXED, __HIP_MEMORY_SCOPE_AGENT);
      }
    }
    __syncthreads();                              // all waves' rh stores drained
    if (tid == 0)
      __hip_atomic_store(myslot, 2 * t + 1, __ATOMIC_RELAXED, __HIP_MEMORY_SCOPE_AGENT);

    // ---- slot S1: x_{t+1} regs -> LDS; bubble: xz_next ----
    f32x4 xzn = {0.f,0.f,0.f,0.f}, xrn = {0.f,0.f,0.f,0.f}, xhn = {0.f,0.f,0.f,0.f};
    {
      #pragma unroll
      for (int i = 0; i < 8; ++i) {
        int g = tid + i * 256;
        float4 v = xr4[i];
        unsigned short tmp[4] = { f2bf(v.x), f2bf(v.y), f2bf(v.z), f2bf(v.w) };
        *(unsigned long long*)&x_lds[p ^ 1][g >> 7][(g & 127) * 4] = *(unsigned long long*)tmp;
      }
    }
    __syncthreads();
    {
      const unsigned short* xrow = &x_lds[p ^ 1][l16][0];
      #pragma unroll
      for (int k = 0; k < 16; ++k) {
        short8 ax = *(const short8*)(xrow + k * 32 + lhi * 8);
        short8 wz = *(const short8*)(WTz + l16 * 512 + k * 32 + lhi * 8);
        xzn = __builtin_amdgcn_mfma_f32_16x16x32_bf16(ax, wz, xzn, 0, 0, 0);
      }
    }
    // ---- wait barrier 1 (8 parallel read-only polls) ----
    if (tid < GRP) {
      while (__hip_atomic_load(slots + tid * 32, __ATOMIC_RELAXED,
                               __HIP_MEMORY_SCOPE_AGENT) < 2 * t + 1) { }
    }
    __syncthreads();

    // ---- slot S2: issue rh loads; bubble xr_next under them; stage rh ----
    unsigned long long rtmp[8];
    {
      const unsigned long long* rs = (const unsigned long long*)(rhbuf + (size_t)r0 * H_);
      #pragma unroll
      for (int i = 0; i < 8; ++i) {
        int g = tid + i * 256;
        rtmp[i] = __hip_atomic_load(rs + (g >> 7) * 128 + (g & 127),
                                    __ATOMIC_RELAXED, __HIP_MEMORY_SCOPE_AGENT);
      }
    }
    {
      const unsigned short* xrow = &x_lds[p ^ 1][l16][0];
      #pragma unroll
      for (int k = 0; k < 16; ++k) {
        short8 ax = *(const short8*)(xrow + k * 32 + lhi * 8);
        short8 wr = *(const short8*)(WTr + l16 * 512 + k * 32 + lhi * 8);
        xrn = __builtin_amdgcn_mfma_f32_16x16x32_bf16(ax, wr, xrn, 0, 0, 0);
      }
    }
    {
      #pragma unroll
      for (int i = 0; i < 8; ++i) {
        int g = tid + i * 256;
        *(unsigned long long*)&h_lds[g >> 7][(g & 127) * 4] = rtmp[i];
      }
    }
    __syncthreads();

    // ---- phase B: rh@Uh; h update; publish h ----
    f32x4 acc2 = {0.f,0.f,0.f,0.f};
    {
      const unsigned short* rrow = &h_lds[l16][0];
      #pragma unroll
      for (int k = 0; k < 16; ++k) {
        short8 ar = *(const short8*)(rrow + k * 32 + lhi * 8);
        acc2 = __builtin_amdgcn_mfma_f32_16x16x32_bf16(ar, uhr[k], acc2, 0, 0, 0);
      }
    }
    {
      #pragma unroll
      for (int i = 0; i < 4; ++i) {
        int lrow = lhi * 4 + i;
        float hh = tanhf(acc2[i] + xhc[i] + cbh);
        float hn = gh4[i] + z4[i] * hh;
        __hip_atomic_store(hbuf + (size_t)(r0 + lrow) * H_ + gcz, f2bf(hn),
                           __ATOMIC_RELAXED, __HIP_MEMORY_SCOPE_AGENT);
      }
    }
    __syncthreads();                              // all waves' h stores drained
    if (tid == 0)
      __hip_atomic_store(myslot, 2 * t + 2, __ATOMIC_RELAXED, __HIP_MEMORY_SCOPE_AGENT);

    // ---- slot S3: issue x_{t+2} HBM prefetch (lands during W2/S4) ----
    {
      int tn = (t + 2 < T_) ? (t + 2) : (T_ - 1);
      const float4* xs = (const float4*)(x + ((size_t)tn * B_ + r0) * D_);
      #pragma unroll
      for (int i = 0; i < 8; ++i) {
        int g = tid + i * 256;
        xr4[i] = xs[(g >> 7) * 128 + (g & 127)];
      }
    }
    // ---- wait barrier 2 ----
    if (tid < GRP) {
      while (__hip_atomic_load(slots + tid * 32, __ATOMIC_RELAXED,
                               __HIP_MEMORY_SCOPE_AGENT) < 2 * t + 2) { }
    }
    __syncthreads();

    // ---- slot S4: issue h loads; bubble xh_next under them; stage h ----
    unsigned long long htmp[8];
    {
      const unsigned long long* hs = (const unsigned long long*)(hbuf + (size_t)r0 * H_);
      #pragma unroll
      for (int i = 0; i < 8; ++i) {
        int g = tid + i * 256;
        htmp[i] = __hip_atomic_load(hs + (g >> 7) * 128 + (g & 127),
                                    __ATOMIC_RELAXED, __HIP_MEMORY_SCOPE_AGENT);
      }
    }
    {
      const unsigned short* xrow = &x_lds[p ^ 1][l16][0];
      #pragma unroll
      for (int k = 0; k < 16; ++k) {
        short8 ax = *(const short8*)(xrow + k * 32 + lhi * 8);
        short8 wh = *(const short8*)(WTh + l16 * 512 + k * 32 + lhi * 8);
        xhn = __builtin_amdgcn_mfma_f32_16x16x32_bf16(ax, wh, xhn, 0, 0, 0);
      }
    }
    {
      #pragma unroll
      for (int i = 0; i < 8; ++i) {
        int g = tid + i * 256;
        *(unsigned long long*)&h_lds[g >> 7][(g & 127) * 4] = htmp[i];
      }
    }
    xzc = xzn; xrc = xrn; xhc = xhn;
    __syncthreads();
  }
}

// ---- final FC: out[b][o] = sum_k h_T[b][k] * fc_w[k][o] + fc_b[o]
__global__ void fc_kernel(const unsigned short* __restrict__ hbuf,
                          const float* __restrict__ fcw,
                          const float* __restrict__ fcb,
                          float* __restrict__ out)
{
  int b = blockIdx.x;
  int o = threadIdx.x;
  float s = fcb[o];
  const unsigned short* hr = hbuf + (size_t)b * H_;
  #pragma unroll 8
  for (int k = 0; k < H_; ++k)
    s = fmaf(bf2f(hr[k]), fcw[k * O_ + o], s);
  out[b * O_ + o] = s;
}

extern "C" void kernel_launch(void* const* d_in, const int* in_sizes, int n_in,
                              void* d_out, int out_size, void* d_ws, size_t ws_size,
                              hipStream_t stream)
{
  const float* x    = (const float*)d_in[0];
  const float* w_z  = (const float*)d_in[1];
  const float* b_z  = (const float*)d_in[2];
  const float* u_z  = (const float*)d_in[3];
  const float* ub_z = (const float*)d_in[4];
  const float* w_r  = (const float*)d_in[5];
  const float* b_r  = (const float*)d_in[6];
  const float* u_r  = (const float*)d_in[7];
  const float* ub_r = (const float*)d_in[8];
  const float* w_h  = (const float*)d_in[9];
  const float* b_h  = (const float*)d_in[10];
  const float* u_h  = (const float*)d_in[11];
  const float* ub_h = (const float*)d_in[12];
  const float* fc_w = (const float*)d_in[13];
  const float* fc_b = (const float*)d_in[14];
  float* out = (float*)d_out;

  char* ws = (char*)d_ws;
  unsigned short* WT = (unsigned short*)ws;  ws += (size_t)1536 * 512 * 2;
  unsigned short* UT = (unsigned short*)ws;  ws += (size_t)1536 * 512 * 2;
  float* cb = (float*)ws;                    ws += 1536 * 4;
  unsigned short* hbuf = (unsigned short*)ws;  ws += (size_t)B_ * H_ * 2;
  unsigned short* rhbuf = (unsigned short*)ws; ws += (size_t)B_ * H_ * 2;
  ws = (char*)(((size_t)ws + 255) & ~(size_t)255);
  int* bar = (int*)ws;

  prep_kernel<<<3072, 256, 0, stream>>>(w_z, u_z, w_r, u_r, w_h, u_h,
                                        b_z, ub_z, b_r, ub_r, b_h, ub_h,
                                        WT, UT, cb, hbuf, bar);
  gru_scan<<<NWG, 256, 0, stream>>>(x, WT, UT, cb, hbuf, rhbuf, bar);
  fc_kernel<<<B_, O_, 0, stream>>>(hbuf, fc_w, fc_b, out);
}